// Round 1
// baseline (78.089 us; speedup 1.0000x reference)
//
#include <hip/hip_runtime.h>

#define DISP_W 1.0f
#define MAT_W  0.1f
#define CD_W   0.5f

constexpr int BB = 4;      // batch
constexpr int NN = 8192;   // points
constexpr int AC = 1024;   // A-points per block
constexpr int BS = 512;    // B-points per LDS segment
constexpr int NPT = 4;     // A-points per thread
constexpr int NA_CHUNKS = NN / AC;   // 8
constexpr int NB_SEGS   = NN / BS;   // 16

__global__ __launch_bounds__(256, 4)
void chamfer_partial(const float* __restrict__ pred_disp,
                     const float* __restrict__ target_disp,
                     const float* __restrict__ tmpl,
                     unsigned int* __restrict__ ws_min)
{
    int blk = blockIdx.x;
    int bSeg = blk % NB_SEGS;   blk /= NB_SEGS;
    int aChk = blk % NA_CHUNKS; blk /= NA_CHUNKS;
    int b    = blk % BB;        blk /= BB;
    int dir  = blk;             // 0: A=pred, B=target ; 1: A=target, B=pred

    const float* aD = (dir ? target_disp : pred_disp) + (size_t)b * NN * 3;
    const float* bD = (dir ? pred_disp : target_disp) + (size_t)b * NN * 3;
    const float* tp = tmpl + (size_t)b * NN * 3;

    __shared__ float sx[BS], sy[BS], sz[BS];
    const int tid = threadIdx.x;
    const int bBase = bSeg * BS;
    for (int k = tid; k < BS; k += 256) {
        int j3 = (bBase + k) * 3;
        sx[k] = tp[j3 + 0] + bD[j3 + 0];
        sy[k] = tp[j3 + 1] + bD[j3 + 1];
        sz[k] = tp[j3 + 2] + bD[j3 + 2];
    }
    __syncthreads();

    float ax[NPT], ay[NPT], az[NPT], m[NPT];
    const int aBase = aChk * AC;
    #pragma unroll
    for (int k = 0; k < NPT; ++k) {
        int i3 = (aBase + k * 256 + tid) * 3;
        ax[k] = tp[i3 + 0] + aD[i3 + 0];
        ay[k] = tp[i3 + 1] + aD[i3 + 1];
        az[k] = tp[i3 + 2] + aD[i3 + 2];
        m[k] = 3.0e38f;
    }

    #pragma unroll 4
    for (int j = 0; j < BS; ++j) {
        float x = sx[j], y = sy[j], z = sz[j];
        #pragma unroll
        for (int k = 0; k < NPT; ++k) {
            float dx = ax[k] - x;
            float dy = ay[k] - y;
            float dz = az[k] - z;
            float d = fmaf(dx, dx, fmaf(dy, dy, dz * dz));
            m[k] = fminf(m[k], d);
        }
    }

    unsigned int* wbase = ws_min + ((size_t)dir * BB + b) * NN;
    #pragma unroll
    for (int k = 0; k < NPT; ++k)
        atomicMin(&wbase[aBase + k * 256 + tid], __float_as_uint(m[k]));
}

__global__ __launch_bounds__(256)
void final_reduce(const float* __restrict__ pred_disp,
                  const float* __restrict__ target_disp,
                  const float* __restrict__ pred_mat,
                  const float* __restrict__ target_mat,
                  const unsigned int* __restrict__ mins,
                  float* __restrict__ out)
{
    const int NDISP = BB * NN * 3;   // 98304
    const int NMINS = 2 * BB * NN;   // 65536

    int gtid = blockIdx.x * blockDim.x + threadIdx.x;
    int gstride = gridDim.x * blockDim.x;

    float dsum = 0.0f;
    for (int i = gtid; i < NDISP; i += gstride)
        dsum += fabsf(pred_disp[i] - target_disp[i]);

    float msum = 0.0f;
    for (int i = gtid; i < NMINS; i += gstride)
        msum += __uint_as_float(mins[i]);

    float acc = dsum * (DISP_W / (float)NDISP)
              + msum * (CD_W / (float)(BB * NN));

    if (gtid < 2 * BB) {
        float d = pred_mat[gtid] - target_mat[gtid];
        acc += d * d * (MAT_W / (float)(2 * BB));
    }

    // wave (64-lane) shuffle reduce
    for (int off = 32; off > 0; off >>= 1)
        acc += __shfl_down(acc, off, 64);

    __shared__ float wsum[4];
    if ((threadIdx.x & 63) == 0) wsum[threadIdx.x >> 6] = acc;
    __syncthreads();
    if (threadIdx.x == 0)
        atomicAdd(out, wsum[0] + wsum[1] + wsum[2] + wsum[3]);
}

extern "C" void kernel_launch(void* const* d_in, const int* in_sizes, int n_in,
                              void* d_out, int out_size, void* d_ws, size_t ws_size,
                              hipStream_t stream) {
    const float* pred_disp   = (const float*)d_in[0];
    const float* pred_mat    = (const float*)d_in[1];
    const float* target_disp = (const float*)d_in[2];
    const float* target_mat  = (const float*)d_in[3];
    const float* tmpl        = (const float*)d_in[4];

    unsigned int* ws_min = (unsigned int*)d_ws;
    float* out = (float*)d_out;

    // ws_min: 2*B*N floats = 256 KB. Fill with 0x7f7f7f7f -> +3.39e38f (positive,
    // so uint ordering == float ordering for the atomicMin trick).
    hipMemsetAsync(ws_min, 0x7f, (size_t)2 * BB * NN * sizeof(unsigned int), stream);
    hipMemsetAsync(d_out, 0, sizeof(float), stream);

    int grid = 2 * BB * NA_CHUNKS * NB_SEGS;  // 1024
    chamfer_partial<<<grid, 256, 0, stream>>>(pred_disp, target_disp, tmpl, ws_min);
    final_reduce<<<128, 256, 0, stream>>>(pred_disp, target_disp, pred_mat, target_mat,
                                          ws_min, out);
}

// Round 2
// 58.060 us; speedup vs baseline: 1.3450x; 1.3450x over previous
//
#include <hip/hip_runtime.h>

#define DISP_W 1.0f
#define MAT_W  0.1f
#define CD_W   0.5f

constexpr int BB = 4;       // batch
constexpr int NN = 8192;    // points
constexpr int THREADS = 128;
constexpr int NPT = 16;     // A-points per thread
constexpr int AC = NPT * THREADS;     // 2048 A-points per block
constexpr int BS = 128;               // B-points per LDS segment
constexpr int NA_CHUNKS = NN / AC;    // 4
constexpr int NB_SEGS   = NN / BS;    // 64

__global__ __launch_bounds__(THREADS, 4)
void chamfer_partial(const float* __restrict__ pred_disp,
                     const float* __restrict__ target_disp,
                     const float* __restrict__ tmpl,
                     unsigned int* __restrict__ ws_min)
{
    int blk = blockIdx.x;
    int bSeg = blk % NB_SEGS;   blk /= NB_SEGS;
    int aChk = blk % NA_CHUNKS; blk /= NA_CHUNKS;
    int b    = blk % BB;        blk /= BB;
    int dir  = blk;             // 0: A=pred,B=target ; 1: A=target,B=pred

    const float* aD = (dir ? target_disp : pred_disp) + (size_t)b * NN * 3;
    const float* bD = (dir ? pred_disp : target_disp) + (size_t)b * NN * 3;
    const float* tp = tmpl + (size_t)b * NN * 3;

    // B-point j staged as (hx,hy,hz,cb) = (-2bx,-2by,-2bz,|b|^2):
    //   |a-b|^2 = |a|^2 + (cb + a.h)  -> inner body = 3 fma + 1 fmin
    __shared__ float4 sB[BS];
    const int tid = threadIdx.x;
    const int bBase = bSeg * BS;
    for (int k = tid; k < BS; k += THREADS) {
        int j3 = (bBase + k) * 3;
        float x = tp[j3 + 0] + bD[j3 + 0];
        float y = tp[j3 + 1] + bD[j3 + 1];
        float z = tp[j3 + 2] + bD[j3 + 2];
        float c = fmaf(x, x, fmaf(y, y, z * z));
        sB[k] = make_float4(-2.0f * x, -2.0f * y, -2.0f * z, c);
    }
    __syncthreads();

    float ax[NPT], ay[NPT], az[NPT], ca[NPT], m[NPT];
    const int aBase = aChk * AC;
    #pragma unroll
    for (int k = 0; k < NPT; ++k) {
        int i3 = (aBase + k * THREADS + tid) * 3;
        ax[k] = tp[i3 + 0] + aD[i3 + 0];
        ay[k] = tp[i3 + 1] + aD[i3 + 1];
        az[k] = tp[i3 + 2] + aD[i3 + 2];
        ca[k] = fmaf(ax[k], ax[k], fmaf(ay[k], ay[k], az[k] * az[k]));
        m[k] = 1.0e30f;
    }

    #pragma unroll 2
    for (int j = 0; j < BS; ++j) {
        float4 c = sB[j];               // one ds_read_b128 broadcast per 16 pairs
        #pragma unroll
        for (int k = 0; k < NPT; ++k) {
            float s = fmaf(az[k], c.z, c.w);
            s = fmaf(ay[k], c.y, s);
            s = fmaf(ax[k], c.x, s);
            m[k] = fminf(m[k], s);
        }
    }

    unsigned int* wbase = ws_min + ((size_t)dir * BB + b) * NN;
    #pragma unroll
    for (int k = 0; k < NPT; ++k) {
        float d = fmaxf(m[k] + ca[k], 0.0f);   // clamp: keep uint ordering valid
        atomicMin(&wbase[aBase + k * THREADS + tid], __float_as_uint(d));
    }
}

__global__ __launch_bounds__(256)
void final_reduce(const float* __restrict__ pred_disp,
                  const float* __restrict__ target_disp,
                  const float* __restrict__ pred_mat,
                  const float* __restrict__ target_mat,
                  const unsigned int* __restrict__ mins,
                  float* __restrict__ out)
{
    const int NDISP = BB * NN * 3;   // 98304
    const int NMINS = 2 * BB * NN;   // 65536

    int gtid = blockIdx.x * blockDim.x + threadIdx.x;
    int gstride = gridDim.x * blockDim.x;

    float dsum = 0.0f;
    for (int i = gtid; i < NDISP; i += gstride)
        dsum += fabsf(pred_disp[i] - target_disp[i]);

    float msum = 0.0f;
    for (int i = gtid; i < NMINS; i += gstride)
        msum += __uint_as_float(mins[i]);

    float acc = dsum * (DISP_W / (float)NDISP)
              + msum * (CD_W / (float)(BB * NN));

    if (gtid < 2 * BB) {
        float d = pred_mat[gtid] - target_mat[gtid];
        acc += d * d * (MAT_W / (float)(2 * BB));
    }

    for (int off = 32; off > 0; off >>= 1)
        acc += __shfl_down(acc, off, 64);

    __shared__ float wsum[4];
    if ((threadIdx.x & 63) == 0) wsum[threadIdx.x >> 6] = acc;
    __syncthreads();
    if (threadIdx.x == 0)
        atomicAdd(out, wsum[0] + wsum[1] + wsum[2] + wsum[3]);
}

extern "C" void kernel_launch(void* const* d_in, const int* in_sizes, int n_in,
                              void* d_out, int out_size, void* d_ws, size_t ws_size,
                              hipStream_t stream) {
    const float* pred_disp   = (const float*)d_in[0];
    const float* pred_mat    = (const float*)d_in[1];
    const float* target_disp = (const float*)d_in[2];
    const float* target_mat  = (const float*)d_in[3];
    const float* tmpl        = (const float*)d_in[4];

    unsigned int* ws_min = (unsigned int*)d_ws;
    float* out = (float*)d_out;

    // 0x7f7f7f7f -> +3.39e38f; positive, so uint ordering == float ordering.
    hipMemsetAsync(ws_min, 0x7f, (size_t)2 * BB * NN * sizeof(unsigned int), stream);
    hipMemsetAsync(d_out, 0, sizeof(float), stream);

    int grid = 2 * BB * NA_CHUNKS * NB_SEGS;  // 2048
    chamfer_partial<<<grid, THREADS, 0, stream>>>(pred_disp, target_disp, tmpl, ws_min);
    final_reduce<<<128, 256, 0, stream>>>(pred_disp, target_disp, pred_mat, target_mat,
                                          ws_min, out);
}

// Round 3
// 47.410 us; speedup vs baseline: 1.6471x; 1.2246x over previous
//
#include <hip/hip_runtime.h>

#define DISP_W 1.0f
#define MAT_W  0.1f
#define CD_W   0.5f

typedef _Float16 half8 __attribute__((ext_vector_type(8)));
typedef float f32x16 __attribute__((ext_vector_type(16)));

constexpr int BB = 4;          // batch
constexpr int NN = 8192;       // points per cloud
constexpr int THREADS = 256;   // 4 waves
constexpr int IB = 128;        // rows (pred pts) per block = 4 waves x 32
constexpr int JR = 1024;       // cols (target pts) per block
constexpr int NIB = NN / IB;   // 64
constexpr int NJB = NN / JR;   // 8
constexpr int NCHUNK = JR / 32;// 32 j-chunks per block sweep

// One MFMA tile = 32x32 pairwise distances. K=16 slot layout (A_k * B_k summed):
//  A: [xh yh zh  xh yh zh  xl yl | zl cah cal 1 1 0 0 0]
//  B: [uxh uyh uzh uxl uyl uzl uxh uyh | uzh 1 1 cbh cbl 0 0 0]   (u = -2*target)
// dot = -2*a.b (hi/lo compensated) + ca + cb = |a-b|^2 to ~f32 precision.
__global__ __launch_bounds__(THREADS, 3)
void chamfer_mfma(const float* __restrict__ pred_disp,
                  const float* __restrict__ target_disp,
                  const float* __restrict__ tmpl,
                  unsigned int* __restrict__ ws_min)
{
    int bx = blockIdx.x;
    int jBlk = bx & (NJB - 1);
    int iBlk = (bx >> 3) & (NIB - 1);
    int b    = bx >> 9;

    const float* pD = pred_disp   + (size_t)b * NN * 3;
    const float* tD = target_disp + (size_t)b * NN * 3;
    const float* tp = tmpl        + (size_t)b * NN * 3;

    __shared__ half8 sBhi[JR];      // 16 KB
    __shared__ half8 sBlo[JR];      // 16 KB
    __shared__ float colw[4 * JR];  // 16 KB

    const int tid  = threadIdx.x;
    const int lane = tid & 63;
    const int w    = tid >> 6;     // wave id 0..3
    const int hi   = lane >> 5;    // k-half selector
    const int li   = lane & 31;

    // ---- stage B fragments (target points) into LDS ----
    const int jBase = jBlk * JR;
    #pragma unroll
    for (int k = 0; k < JR / THREADS; ++k) {
        int j  = k * THREADS + tid;
        int j3 = (jBase + j) * 3;
        float x = tp[j3 + 0] + tD[j3 + 0];
        float y = tp[j3 + 1] + tD[j3 + 1];
        float z = tp[j3 + 2] + tD[j3 + 2];
        float cb = fmaf(x, x, fmaf(y, y, z * z));
        float ux = -2.0f * x, uy = -2.0f * y, uz = -2.0f * z;
        _Float16 uxh = (_Float16)ux; _Float16 uxl = (_Float16)(ux - (float)uxh);
        _Float16 uyh = (_Float16)uy; _Float16 uyl = (_Float16)(uy - (float)uyh);
        _Float16 uzh = (_Float16)uz; _Float16 uzl = (_Float16)(uz - (float)uzh);
        _Float16 cbh = (_Float16)cb; _Float16 cbl = (_Float16)(cb - (float)cbh);
        half8 vhi, vlo;
        vhi[0]=uxh; vhi[1]=uyh; vhi[2]=uzh; vhi[3]=uxl; vhi[4]=uyl; vhi[5]=uzl; vhi[6]=uxh; vhi[7]=uyh;
        vlo[0]=uzh; vlo[1]=(_Float16)1.0f; vlo[2]=(_Float16)1.0f; vlo[3]=cbh; vlo[4]=cbl;
        vlo[5]=(_Float16)0.0f; vlo[6]=(_Float16)0.0f; vlo[7]=(_Float16)0.0f;
        sBhi[j] = vhi;
        sBlo[j] = vlo;
    }

    // ---- build A fragment (this wave's 32 pred points; lanes l and l+32 share a point) ----
    int i  = iBlk * IB + w * 32 + li;
    int i3 = i * 3;
    float ax = tp[i3 + 0] + pD[i3 + 0];
    float ay = tp[i3 + 1] + pD[i3 + 1];
    float az = tp[i3 + 2] + pD[i3 + 2];
    float ca = fmaf(ax, ax, fmaf(ay, ay, az * az));
    _Float16 xh = (_Float16)ax; _Float16 xl = (_Float16)(ax - (float)xh);
    _Float16 yh = (_Float16)ay; _Float16 yl = (_Float16)(ay - (float)yh);
    _Float16 zh = (_Float16)az; _Float16 zl = (_Float16)(az - (float)zh);
    _Float16 cah = (_Float16)ca; _Float16 cal = (_Float16)(ca - (float)cah);
    half8 aF;
    if (hi == 0) {
        aF[0]=xh; aF[1]=yh; aF[2]=zh; aF[3]=xh; aF[4]=yh; aF[5]=zh; aF[6]=xl; aF[7]=yl;
    } else {
        aF[0]=zl; aF[1]=cah; aF[2]=cal; aF[3]=(_Float16)1.0f; aF[4]=(_Float16)1.0f;
        aF[5]=(_Float16)0.0f; aF[6]=(_Float16)0.0f; aF[7]=(_Float16)0.0f;
    }

    __syncthreads();

    f32x16 kZero = {0.f,0.f,0.f,0.f, 0.f,0.f,0.f,0.f, 0.f,0.f,0.f,0.f, 0.f,0.f,0.f,0.f};
    const half8* baseB = hi ? sBlo : sBhi;   // per-lane k-half source
    float rm[16];
    #pragma unroll
    for (int r = 0; r < 16; ++r) rm[r] = 1.0e30f;

    #pragma unroll 2
    for (int c = 0; c < NCHUNK; ++c) {
        half8 bF = baseB[c * 32 + li];
        f32x16 acc = __builtin_amdgcn_mfma_f32_32x32x16_f16(aF, bF, kZero, 0, 0, 0);
        // row running mins (row = (r&3)+8*(r>>2)+4*hi, col = li)
        #pragma unroll
        for (int r = 0; r < 16; ++r) rm[r] = fminf(rm[r], acc[r]);
        // col partial: min over this lane's 16 rows
        float m0 = fminf(acc[0], acc[1]),   m1 = fminf(acc[2], acc[3]);
        float m2 = fminf(acc[4], acc[5]),   m3 = fminf(acc[6], acc[7]);
        float m4 = fminf(acc[8], acc[9]),   m5 = fminf(acc[10], acc[11]);
        float m6 = fminf(acc[12], acc[13]), m7 = fminf(acc[14], acc[15]);
        m0 = fminf(m0, m1); m2 = fminf(m2, m3); m4 = fminf(m4, m5); m6 = fminf(m6, m7);
        float v = fminf(fminf(m0, m2), fminf(m4, m6));
        v = fminf(v, __shfl_xor(v, 32, 64));       // combine hi halves -> min over 32 rows
        if (lane < 32) colw[w * JR + c * 32 + lane] = v;
    }

    // ---- row mins: butterfly over the 32 col-lanes, then global atomicMin ----
    #pragma unroll
    for (int r = 0; r < 16; ++r) {
        float v = rm[r];
        v = fminf(v, __shfl_xor(v, 1, 64));
        v = fminf(v, __shfl_xor(v, 2, 64));
        v = fminf(v, __shfl_xor(v, 4, 64));
        v = fminf(v, __shfl_xor(v, 8, 64));
        v = fminf(v, __shfl_xor(v, 16, 64));
        rm[r] = v;
    }
    if (li == 0) {
        unsigned int* rowws = ws_min + (size_t)b * NN + iBlk * IB + w * 32;
        #pragma unroll
        for (int r = 0; r < 16; ++r) {
            int row = (r & 3) + 8 * (r >> 2) + 4 * hi;
            atomicMin(&rowws[row], __float_as_uint(fmaxf(rm[r], 0.0f)));
        }
    }

    // ---- col mins: combine 4 waves, one atomic per column ----
    __syncthreads();
    unsigned int* colws = ws_min + (size_t)(BB + b) * NN + jBase;
    for (int cc = tid; cc < JR; cc += THREADS) {
        float v = fminf(fminf(colw[cc], colw[JR + cc]),
                        fminf(colw[2 * JR + cc], colw[3 * JR + cc]));
        atomicMin(&colws[cc], __float_as_uint(fmaxf(v, 0.0f)));
    }
}

__global__ __launch_bounds__(256)
void final_reduce(const float* __restrict__ pred_disp,
                  const float* __restrict__ target_disp,
                  const float* __restrict__ pred_mat,
                  const float* __restrict__ target_mat,
                  const unsigned int* __restrict__ mins,
                  float* __restrict__ out)
{
    const int NDISP = BB * NN * 3;   // 98304
    const int NMINS = 2 * BB * NN;   // 65536

    int gtid = blockIdx.x * blockDim.x + threadIdx.x;
    int gstride = gridDim.x * blockDim.x;

    float dsum = 0.0f;
    for (int i = gtid; i < NDISP; i += gstride)
        dsum += fabsf(pred_disp[i] - target_disp[i]);

    float msum = 0.0f;
    for (int i = gtid; i < NMINS; i += gstride)
        msum += __uint_as_float(mins[i]);

    float acc = dsum * (DISP_W / (float)NDISP)
              + msum * (CD_W / (float)(BB * NN));

    if (gtid < 2 * BB) {
        float d = pred_mat[gtid] - target_mat[gtid];
        acc += d * d * (MAT_W / (float)(2 * BB));
    }

    for (int off = 32; off > 0; off >>= 1)
        acc += __shfl_down(acc, off, 64);

    __shared__ float wsum[4];
    if ((threadIdx.x & 63) == 0) wsum[threadIdx.x >> 6] = acc;
    __syncthreads();
    if (threadIdx.x == 0)
        atomicAdd(out, wsum[0] + wsum[1] + wsum[2] + wsum[3]);
}

extern "C" void kernel_launch(void* const* d_in, const int* in_sizes, int n_in,
                              void* d_out, int out_size, void* d_ws, size_t ws_size,
                              hipStream_t stream) {
    const float* pred_disp   = (const float*)d_in[0];
    const float* pred_mat    = (const float*)d_in[1];
    const float* target_disp = (const float*)d_in[2];
    const float* target_mat  = (const float*)d_in[3];
    const float* tmpl        = (const float*)d_in[4];

    unsigned int* ws_min = (unsigned int*)d_ws;
    float* out = (float*)d_out;

    // 0x7f7f7f7f -> +3.39e38f (positive => uint order == float order for atomicMin)
    hipMemsetAsync(ws_min, 0x7f, (size_t)2 * BB * NN * sizeof(unsigned int), stream);
    hipMemsetAsync(d_out, 0, sizeof(float), stream);

    int grid = BB * NIB * NJB;  // 2048
    chamfer_mfma<<<grid, THREADS, 0, stream>>>(pred_disp, target_disp, tmpl, ws_min);
    final_reduce<<<128, 256, 0, stream>>>(pred_disp, target_disp, pred_mat, target_mat,
                                          ws_min, out);
}